// Round 1
// baseline (463.754 us; speedup 1.0000x reference)
//
#include <hip/hip_runtime.h>
#include <hip/hip_bf16.h>
#include <cstdint>

typedef __bf16 bf16x8 __attribute__((ext_vector_type(8)));
typedef __bf16 bf16x4 __attribute__((ext_vector_type(4)));
typedef float  f32x4  __attribute__((ext_vector_type(4)));

#define NN 50000
#define EE 800000
#define ND 128
#define HID 128

__device__ __forceinline__ f32x4 mfma_bf16(bf16x8 a, bf16x8 b, f32x4 c) {
  return __builtin_amdgcn_mfma_f32_16x16x32_bf16(a, b, c, 0, 0, 0);
}
__device__ __forceinline__ float fast_sigmoid(float x) {
  return __fdividef(1.f, 1.f + __expf(-x));
}
__device__ __forceinline__ float fast_silu(float x) {
  return __fdividef(x, 1.f + __expf(-x));
}
__device__ __forceinline__ float fast_tanh(float x) {
  float cx = fminf(fmaxf(x, -15.f), 15.f);
  float e = __expf(2.f * cx);
  return __fdividef(e - 1.f, e + 1.f);
}

// ---- f32 -> bf16 conversion, 8 elems/thread ----
__global__ void cvt_f32_bf16(const float* __restrict__ src, __bf16* __restrict__ dst, int n8) {
  int i = blockIdx.x * blockDim.x + threadIdx.x;
  if (i >= n8) return;
  const float4* s = reinterpret_cast<const float4*>(src) + (size_t)i * 2;
  float4 a = s[0], b = s[1];
  bf16x8 v;
  v[0] = (__bf16)a.x; v[1] = (__bf16)a.y; v[2] = (__bf16)a.z; v[3] = (__bf16)a.w;
  v[4] = (__bf16)b.x; v[5] = (__bf16)b.y; v[6] = (__bf16)b.z; v[7] = (__bf16)b.w;
  reinterpret_cast<bf16x8*>(dst)[i] = v;
}

// ---- edge MLP + scatter ----
#define TILE_E 64
#define A_PAD 168   // 160 + 8 (keeps rows 16B aligned, breaks bank stride)
#define H_PAD 136   // 128 + 8

__global__ __launch_bounds__(512) void edge_mlp(
    const __bf16* __restrict__ xb,
    const int*    __restrict__ ei,    // [2*E]: src then dst
    const float*  __restrict__ ea,    // [E,32]
    const __bf16* __restrict__ W1b,   // [128,160] row-major (out,in)
    const float*  __restrict__ b1,
    const __bf16* __restrict__ W2b,   // [128,128]
    const float*  __restrict__ b2,
    float* __restrict__ agg,          // [N,128] f32, atomically accumulated
    int E, int ntiles)
{
  __shared__ __bf16 Als[TILE_E][A_PAD];
  __shared__ __bf16 H1ls[TILE_E][H_PAD];

  const int tid = threadIdx.x;
  const int w  = tid >> 6;       // wave 0..7 -> output col tile
  const int l  = tid & 63;
  const int l4 = l >> 4;         // 0..3
  const int lm = l & 15;
  const int jw = w * 16 + lm;    // this lane's output column (B-frag row)

  // B fragments in registers, loaded once per block.
  bf16x8 bw1[5];
#pragma unroll
  for (int kt = 0; kt < 5; ++kt)
    bw1[kt] = *reinterpret_cast<const bf16x8*>(W1b + (size_t)jw * 160 + kt * 32 + l4 * 8);
  bf16x8 bw2[4];
#pragma unroll
  for (int kt = 0; kt < 4; ++kt)
    bw2[kt] = *reinterpret_cast<const bf16x8*>(W2b + (size_t)jw * 128 + kt * 32 + l4 * 8);
  const float b1v = b1[jw];
  const float b2v = b2[jw];
  const int* srcp = ei;
  const int* dstp = ei + E;

  for (int tile = blockIdx.x; tile < ntiles; tile += gridDim.x) {
    const int e0 = tile * TILE_E;

    // ---- stage A tile: [64 edges][x(128) | edge_attr(32)] as bf16 ----
#pragma unroll
    for (int it = 0; it < 2; ++it) {        // x part: 64*16 = 1024 chunks of 8 bf16
      int idx = it * 512 + tid;
      int e = idx >> 4, q = idx & 15;
      int s = srcp[e0 + e];
      bf16x8 v = *reinterpret_cast<const bf16x8*>(xb + (size_t)s * ND + q * 8);
      *reinterpret_cast<bf16x8*>(&Als[e][q * 8]) = v;
    }
    {                                        // edge_attr part: 64*8 = 512 float4
      int e = tid >> 3, q = tid & 7;
      float4 v = reinterpret_cast<const float4*>(ea)[(size_t)(e0 + e) * 8 + q];
      bf16x4 h;
      h[0] = (__bf16)v.x; h[1] = (__bf16)v.y; h[2] = (__bf16)v.z; h[3] = (__bf16)v.w;
      *reinterpret_cast<bf16x4*>(&Als[e][ND + q * 4]) = h;
    }
    __syncthreads();

    // ---- layer 1: h1 = silu(A @ W1^T + b1), K=160 ----
#pragma unroll
    for (int rt = 0; rt < 4; ++rt) {
      const int er = rt * 16;
      f32x4 acc = {0.f, 0.f, 0.f, 0.f};
#pragma unroll
      for (int kt = 0; kt < 5; ++kt) {
        bf16x8 a = *reinterpret_cast<const bf16x8*>(&Als[er + lm][kt * 32 + l4 * 8]);
        acc = mfma_bf16(a, bw1[kt], acc);
      }
#pragma unroll
      for (int rr = 0; rr < 4; ++rr) {
        float hv = fast_silu(acc[rr] + b1v);
        H1ls[er + l4 * 4 + rr][jw] = (__bf16)hv;
      }
    }
    __syncthreads();

    // ---- layer 2: m = silu(h1 @ W2^T + b2), K=128; scatter atomicAdd ----
#pragma unroll
    for (int rt = 0; rt < 4; ++rt) {
      const int er = rt * 16;
      f32x4 acc = {0.f, 0.f, 0.f, 0.f};
#pragma unroll
      for (int kt = 0; kt < 4; ++kt) {
        bf16x8 a = *reinterpret_cast<const bf16x8*>(&H1ls[er + lm][kt * 32 + l4 * 8]);
        acc = mfma_bf16(a, bw2[kt], acc);
      }
#pragma unroll
      for (int rr = 0; rr < 4; ++rr) {
        float mv = fast_silu(acc[rr] + b2v);
        int d = dstp[e0 + er + l4 * 4 + rr];
        atomicAdd(agg + (size_t)d * HID + jw, mv);
      }
    }
    __syncthreads();
  }
}

// ---- GRU cell ----
__global__ __launch_bounds__(256) void gru_kernel(
    const float*  __restrict__ agg,
    const __bf16* __restrict__ xb,
    const float*  __restrict__ x,
    const __bf16* __restrict__ Wih, const float* __restrict__ bih,  // [384,128]
    const __bf16* __restrict__ Whh, const float* __restrict__ bhh,  // [384,128]
    float* __restrict__ out, int N)
{
  __shared__ __bf16 Ag[64][H_PAD];
  const int tid = threadIdx.x;
  const int n0 = blockIdx.x * 64;

  // stage agg rows -> bf16 LDS (64 rows * 32 float4)
#pragma unroll
  for (int it = 0; it < 8; ++it) {
    int idx = it * 256 + tid;
    int r = idx >> 5, q = idx & 31;
    int n = n0 + r;
    float4 v = make_float4(0.f, 0.f, 0.f, 0.f);
    if (n < N) v = reinterpret_cast<const float4*>(agg)[(size_t)n * 32 + q];
    bf16x4 h;
    h[0] = (__bf16)v.x; h[1] = (__bf16)v.y; h[2] = (__bf16)v.z; h[3] = (__bf16)v.w;
    *reinterpret_cast<bf16x4*>(&Ag[r][q * 4]) = h;
  }
  __syncthreads();

  const int w = tid >> 6, l = tid & 63;
  const int l4 = l >> 4, lm = l & 15;
  const int arow = w * 16 + lm;       // A-frag row (input side)
  const int nrow = n0 + arow;

  bf16x8 aA[4], aX[4];
#pragma unroll
  for (int kt = 0; kt < 4; ++kt) {
    aA[kt] = *reinterpret_cast<const bf16x8*>(&Ag[arow][kt * 32 + l4 * 8]);
    bf16x8 z8 = {};
    aX[kt] = (nrow < N)
      ? *reinterpret_cast<const bf16x8*>(xb + (size_t)nrow * ND + kt * 32 + l4 * 8)
      : z8;
  }

  float rg[8][4], zg[8][4];

  // phase R: cols [0,128)
#pragma unroll
  for (int ct = 0; ct < 8; ++ct) {
    int j = ct * 16 + lm;
    f32x4 acc = {0.f, 0.f, 0.f, 0.f};
#pragma unroll
    for (int kt = 0; kt < 4; ++kt)
      acc = mfma_bf16(aA[kt], *reinterpret_cast<const bf16x8*>(Wih + (size_t)j * ND + kt * 32 + l4 * 8), acc);
#pragma unroll
    for (int kt = 0; kt < 4; ++kt)
      acc = mfma_bf16(aX[kt], *reinterpret_cast<const bf16x8*>(Whh + (size_t)j * ND + kt * 32 + l4 * 8), acc);
    float bias = bih[j] + bhh[j];
#pragma unroll
    for (int rr = 0; rr < 4; ++rr) rg[ct][rr] = fast_sigmoid(acc[rr] + bias);
  }
  // phase Z: cols [128,256)
#pragma unroll
  for (int ct = 0; ct < 8; ++ct) {
    int j = 128 + ct * 16 + lm;
    f32x4 acc = {0.f, 0.f, 0.f, 0.f};
#pragma unroll
    for (int kt = 0; kt < 4; ++kt)
      acc = mfma_bf16(aA[kt], *reinterpret_cast<const bf16x8*>(Wih + (size_t)j * ND + kt * 32 + l4 * 8), acc);
#pragma unroll
    for (int kt = 0; kt < 4; ++kt)
      acc = mfma_bf16(aX[kt], *reinterpret_cast<const bf16x8*>(Whh + (size_t)j * ND + kt * 32 + l4 * 8), acc);
    float bias = bih[j] + bhh[j];
#pragma unroll
    for (int rr = 0; rr < 4; ++rr) zg[ct][rr] = fast_sigmoid(acc[rr] + bias);
  }
  // phase N: cols [256,384) ; n = tanh(i_n + b_ihn + r*(h_n + b_hhn)) ; out
#pragma unroll
  for (int ct = 0; ct < 8; ++ct) {
    int j = 256 + ct * 16 + lm;
    f32x4 ai = {0.f, 0.f, 0.f, 0.f}, ah = {0.f, 0.f, 0.f, 0.f};
#pragma unroll
    for (int kt = 0; kt < 4; ++kt)
      ai = mfma_bf16(aA[kt], *reinterpret_cast<const bf16x8*>(Wih + (size_t)j * ND + kt * 32 + l4 * 8), ai);
#pragma unroll
    for (int kt = 0; kt < 4; ++kt)
      ah = mfma_bf16(aX[kt], *reinterpret_cast<const bf16x8*>(Whh + (size_t)j * ND + kt * 32 + l4 * 8), ah);
    float bi = bih[j], bh = bhh[j];
#pragma unroll
    for (int rr = 0; rr < 4; ++rr) {
      int node = n0 + w * 16 + l4 * 4 + rr;   // C-frag row (output side)
      if (node < N) {
        int jj = ct * 16 + lm;
        float nv = fast_tanh(ai[rr] + bi + rg[ct][rr] * (ah[rr] + bh));
        float xv = x[(size_t)node * ND + jj];
        float zv = zg[ct][rr];
        out[(size_t)node * ND + jj] = (1.f - zv) * nv + zv * xv;
      }
    }
  }
}

extern "C" void kernel_launch(void* const* d_in, const int* in_sizes, int n_in,
                              void* d_out, int out_size, void* d_ws, size_t ws_size,
                              hipStream_t stream) {
  const float* x   = (const float*)d_in[0];
  const int*   ei  = (const int*)d_in[1];
  const float* ea  = (const float*)d_in[2];
  const float* W1  = (const float*)d_in[3];
  const float* b1  = (const float*)d_in[4];
  const float* W2  = (const float*)d_in[5];
  const float* b2  = (const float*)d_in[6];
  const float* Wih = (const float*)d_in[7];
  const float* bih = (const float*)d_in[8];
  const float* Whh = (const float*)d_in[9];
  const float* bhh = (const float*)d_in[10];
  float* out = (float*)d_out;
  const int N = NN, E = EE;

  char* ws = (char*)d_ws;
  size_t off = 0;
  float*  agg  = (float*)(ws + off);  off += (size_t)N * ND * 4;
  __bf16* xb   = (__bf16*)(ws + off); off += (size_t)N * ND * 2;
  __bf16* W1b  = (__bf16*)(ws + off); off += 128 * 160 * 2;
  __bf16* W2b  = (__bf16*)(ws + off); off += 128 * 128 * 2;
  __bf16* Wihb = (__bf16*)(ws + off); off += 384 * 128 * 2;
  __bf16* Whhb = (__bf16*)(ws + off); off += 384 * 128 * 2;

  hipMemsetAsync(agg, 0, (size_t)N * ND * 4, stream);
  cvt_f32_bf16<<<(N * ND / 8 + 255) / 256, 256, 0, stream>>>(x, xb, N * ND / 8);
  cvt_f32_bf16<<<(128 * 160 / 8 + 255) / 256, 256, 0, stream>>>(W1, W1b, 128 * 160 / 8);
  cvt_f32_bf16<<<(128 * 128 / 8 + 255) / 256, 256, 0, stream>>>(W2, W2b, 128 * 128 / 8);
  cvt_f32_bf16<<<(384 * 128 / 8 + 255) / 256, 256, 0, stream>>>(Wih, Wihb, 384 * 128 / 8);
  cvt_f32_bf16<<<(384 * 128 / 8 + 255) / 256, 256, 0, stream>>>(Whh, Whhb, 384 * 128 / 8);

  int ntiles = E / TILE_E;   // 12500
  edge_mlp<<<2500, 512, 0, stream>>>(xb, ei, ea, W1b, b1, W2b, b2, agg, E, ntiles);
  gru_kernel<<<(N + 63) / 64, 256, 0, stream>>>(agg, xb, x, Wihb, bih, Whhb, bhh, out, N);
}

// Round 2
// 387.797 us; speedup vs baseline: 1.1959x; 1.1959x over previous
//
#include <hip/hip_runtime.h>
#include <hip/hip_bf16.h>
#include <cstdint>

typedef __bf16 bf16x8 __attribute__((ext_vector_type(8)));
typedef __bf16 bf16x4 __attribute__((ext_vector_type(4)));
typedef float  f32x4  __attribute__((ext_vector_type(4)));

#define ND 128
#define HID 128

__device__ __forceinline__ f32x4 mfma_bf16(bf16x8 a, bf16x8 b, f32x4 c) {
  return __builtin_amdgcn_mfma_f32_16x16x32_bf16(a, b, c, 0, 0, 0);
}
__device__ __forceinline__ float fast_sigmoid(float x) {
  return __fdividef(1.f, 1.f + __expf(-x));
}
__device__ __forceinline__ float fast_silu(float x) {
  return __fdividef(x, 1.f + __expf(-x));
}
__device__ __forceinline__ float fast_tanh(float x) {
  float cx = fminf(fmaxf(x, -15.f), 15.f);
  float e = __expf(2.f * cx);
  return __fdividef(e - 1.f, e + 1.f);
}

// ---- f32 -> bf16 conversion, 8 elems/thread ----
__global__ void cvt_f32_bf16(const float* __restrict__ src, __bf16* __restrict__ dst, int n8) {
  int i = blockIdx.x * blockDim.x + threadIdx.x;
  if (i >= n8) return;
  const float4* s = reinterpret_cast<const float4*>(src) + (size_t)i * 2;
  float4 a = s[0], b = s[1];
  bf16x8 v;
  v[0] = (__bf16)a.x; v[1] = (__bf16)a.y; v[2] = (__bf16)a.z; v[3] = (__bf16)a.w;
  v[4] = (__bf16)b.x; v[5] = (__bf16)b.y; v[6] = (__bf16)b.z; v[7] = (__bf16)b.w;
  reinterpret_cast<bf16x8*>(dst)[i] = v;
}

// ================= sort machinery =================
__global__ void k_hist(const int* __restrict__ dst, int* __restrict__ counts, int E) {
  int e = blockIdx.x * 256 + threadIdx.x;
  if (e < E) atomicAdd(&counts[dst[e]], 1);
}

__global__ void k_blocksum(const int* __restrict__ counts, int* __restrict__ bsum) {
  __shared__ int sd[256];
  int t = threadIdx.x;
  sd[t] = counts[blockIdx.x * 256 + t];
  __syncthreads();
  for (int d = 128; d > 0; d >>= 1) { if (t < d) sd[t] += sd[t + d]; __syncthreads(); }
  if (!t) bsum[blockIdx.x] = sd[0];
}

__global__ void k_scan_bsum(int* __restrict__ bsum, int nb) {  // nb <= 256, 1 block
  __shared__ int sd[256];
  int t = threadIdx.x;
  int v = (t < nb) ? bsum[t] : 0;
  sd[t] = v;
  __syncthreads();
  for (int d = 1; d < 256; d <<= 1) {
    int u = (t >= d) ? sd[t - d] : 0;
    __syncthreads();
    sd[t] += u;
    __syncthreads();
  }
  if (t < nb) bsum[t] = sd[t] - v;  // exclusive
}

__global__ void k_scan_write(const int* __restrict__ counts, const int* __restrict__ bsum,
                             int* __restrict__ offsets, int* __restrict__ cursor) {
  __shared__ int sd[256];
  int t = threadIdx.x, b = blockIdx.x;
  int i = b * 256 + t;
  int c = counts[i];
  sd[t] = c;
  __syncthreads();
  for (int d = 1; d < 256; d <<= 1) {
    int u = (t >= d) ? sd[t - d] : 0;
    __syncthreads();
    sd[t] += u;
    __syncthreads();
  }
  int excl = bsum[b] + sd[t] - c;
  offsets[i] = excl;
  cursor[i]  = excl;
  if (b == (int)gridDim.x - 1 && t == 255) offsets[i + 1] = excl + c;  // == E
}

__global__ void k_spos(const int* __restrict__ dst, int* __restrict__ cursor,
                       int* __restrict__ spos, int E) {
  int e = blockIdx.x * 256 + threadIdx.x;
  if (e < E) spos[e] = atomicAdd(&cursor[dst[e]], 1);
}

// ================= edge MLP =================
#define TILE_E 64
#define A_PAD 168   // 160 + 8
#define H_PAD 136   // 128 + 8

template <int SORT>
__global__ __launch_bounds__(512) void edge_mlp(
    const __bf16* __restrict__ xb,
    const int*    __restrict__ ei,     // [2*E]: src then dst
    const float*  __restrict__ ea,     // [E,32]
    const __bf16* __restrict__ W1b,    // [128,160]
    const float*  __restrict__ b1,
    const __bf16* __restrict__ W2b,    // [128,128]
    const float*  __restrict__ b2,
    float*  __restrict__ agg,          // SORT==0: f32 atomic target
    __bf16* __restrict__ mbuf,         // SORT==1: [E,128] sorted rows
    const int* __restrict__ spos,      // SORT==1: edge -> sorted row
    int E, int ntiles)
{
  __shared__ __bf16 Als[TILE_E][A_PAD];
  __shared__ __bf16 H1ls[TILE_E][H_PAD];
  __shared__ int sposls[TILE_E];

  const int tid = threadIdx.x;
  const int w  = tid >> 6;
  const int l  = tid & 63;
  const int l4 = l >> 4;
  const int lm = l & 15;
  const int jw = w * 16 + lm;

  bf16x8 bw1[5];
#pragma unroll
  for (int kt = 0; kt < 5; ++kt)
    bw1[kt] = *reinterpret_cast<const bf16x8*>(W1b + (size_t)jw * 160 + kt * 32 + l4 * 8);
  bf16x8 bw2[4];
#pragma unroll
  for (int kt = 0; kt < 4; ++kt)
    bw2[kt] = *reinterpret_cast<const bf16x8*>(W2b + (size_t)jw * 128 + kt * 32 + l4 * 8);
  const float b1v = b1[jw];
  const float b2v = b2[jw];
  const int* srcp = ei;
  const int* dstp = ei + E;

  __bf16* Mls = &Als[0][0];  // reused as [64][H_PAD] after layer 1

  for (int tile = blockIdx.x; tile < ntiles; tile += gridDim.x) {
    const int e0 = tile * TILE_E;

    // ---- stage A tile ----
#pragma unroll
    for (int it = 0; it < 2; ++it) {
      int idx = it * 512 + tid;
      int e = idx >> 4, q = idx & 15;
      int s = srcp[e0 + e];
      bf16x8 v = *reinterpret_cast<const bf16x8*>(xb + (size_t)s * ND + q * 8);
      *reinterpret_cast<bf16x8*>(&Als[e][q * 8]) = v;
    }
    {
      int e = tid >> 3, q = tid & 7;
      float4 v = reinterpret_cast<const float4*>(ea)[(size_t)(e0 + e) * 8 + q];
      bf16x4 h;
      h[0] = (__bf16)v.x; h[1] = (__bf16)v.y; h[2] = (__bf16)v.z; h[3] = (__bf16)v.w;
      *reinterpret_cast<bf16x4*>(&Als[e][ND + q * 4]) = h;
    }
    if (SORT && tid < TILE_E) sposls[tid] = spos[e0 + tid];
    __syncthreads();

    // ---- layer 1 ----
#pragma unroll
    for (int rt = 0; rt < 4; ++rt) {
      const int er = rt * 16;
      f32x4 acc = {0.f, 0.f, 0.f, 0.f};
#pragma unroll
      for (int kt = 0; kt < 5; ++kt) {
        bf16x8 a = *reinterpret_cast<const bf16x8*>(&Als[er + lm][kt * 32 + l4 * 8]);
        acc = mfma_bf16(a, bw1[kt], acc);
      }
#pragma unroll
      for (int rr = 0; rr < 4; ++rr) {
        float hv = fast_silu(acc[rr] + b1v);
        H1ls[er + l4 * 4 + rr][jw] = (__bf16)hv;
      }
    }
    __syncthreads();

    // ---- layer 2 ----
#pragma unroll
    for (int rt = 0; rt < 4; ++rt) {
      const int er = rt * 16;
      f32x4 acc = {0.f, 0.f, 0.f, 0.f};
#pragma unroll
      for (int kt = 0; kt < 4; ++kt) {
        bf16x8 a = *reinterpret_cast<const bf16x8*>(&H1ls[er + lm][kt * 32 + l4 * 8]);
        acc = mfma_bf16(a, bw2[kt], acc);
      }
      if (SORT) {
#pragma unroll
        for (int rr = 0; rr < 4; ++rr) {
          float mv = fast_silu(acc[rr] + b2v);
          Mls[(er + l4 * 4 + rr) * H_PAD + jw] = (__bf16)mv;
        }
      } else {
#pragma unroll
        for (int rr = 0; rr < 4; ++rr) {
          float mv = fast_silu(acc[rr] + b2v);
          int d = dstp[e0 + er + l4 * 4 + rr];
          atomicAdd(agg + (size_t)d * HID + jw, mv);
        }
      }
    }
    __syncthreads();

    if (SORT) {
      // ---- repack: LDS M tile -> coalesced 16B stores at sorted rows ----
#pragma unroll
      for (int it = 0; it < 2; ++it) {
        int idx = it * 512 + tid;
        int row = idx >> 4, q = idx & 15;
        bf16x8 v = *reinterpret_cast<const bf16x8*>(&Mls[row * H_PAD + q * 8]);
        int sp = sposls[row];
        *reinterpret_cast<bf16x8*>(mbuf + (size_t)sp * HID + q * 8) = v;
      }
      __syncthreads();
    }
  }
}

// ================= aggregator: one wave per node =================
__global__ __launch_bounds__(256) void k_aggregate(
    const __bf16* __restrict__ mbuf, const int* __restrict__ offsets,
    __bf16* __restrict__ aggb, int N)
{
  int node = blockIdx.x * 4 + (threadIdx.x >> 6);
  int l = threadIdx.x & 63;
  if (node >= N) return;
  int lo = offsets[node], hi = offsets[node + 1];
  float s0 = 0.f, s1 = 0.f;
  const uint32_t* p = reinterpret_cast<const uint32_t*>(mbuf) + (size_t)lo * 64 + l;
  int r = lo;
  for (; r + 1 < hi; r += 2) {
    uint32_t v0 = p[0];
    uint32_t v1 = p[64];
    p += 128;
    s0 += __uint_as_float(v0 << 16);
    s1 += __uint_as_float(v0 & 0xffff0000u);
    s0 += __uint_as_float(v1 << 16);
    s1 += __uint_as_float(v1 & 0xffff0000u);
  }
  if (r < hi) {
    uint32_t v0 = p[0];
    s0 += __uint_as_float(v0 << 16);
    s1 += __uint_as_float(v0 & 0xffff0000u);
  }
  uint32_t o = (uint32_t)__builtin_bit_cast(unsigned short, (__bf16)s0) |
               ((uint32_t)__builtin_bit_cast(unsigned short, (__bf16)s1) << 16);
  reinterpret_cast<uint32_t*>(aggb)[(size_t)node * 64 + l] = o;
}

// ================= GRU v2: weight-stationary =================
__global__ __launch_bounds__(512) void gru2(
    const __bf16* __restrict__ aggb,
    const __bf16* __restrict__ xb,
    const float*  __restrict__ x,
    const __bf16* __restrict__ Wih, const float* __restrict__ bih,  // [384,128]
    const __bf16* __restrict__ Whh, const float* __restrict__ bhh,
    float* __restrict__ out, int N)
{
  const int tid = threadIdx.x;
  const int w = tid >> 6, l = tid & 63;
  const int l4 = l >> 4, lm = l & 15;
  const int n0 = blockIdx.x * 64;
  const int jr = w * 16 + lm, jz = jr + 128, jn = jr + 256;

  bf16x8 WiR[4], WhR[4], WiZ[4], WhZ[4], WiN[4], WhN[4];
#pragma unroll
  for (int kt = 0; kt < 4; ++kt) {
    int ko = kt * 32 + l4 * 8;
    WiR[kt] = *reinterpret_cast<const bf16x8*>(Wih + (size_t)jr * ND + ko);
    WhR[kt] = *reinterpret_cast<const bf16x8*>(Whh + (size_t)jr * ND + ko);
    WiZ[kt] = *reinterpret_cast<const bf16x8*>(Wih + (size_t)jz * ND + ko);
    WhZ[kt] = *reinterpret_cast<const bf16x8*>(Whh + (size_t)jz * ND + ko);
    WiN[kt] = *reinterpret_cast<const bf16x8*>(Wih + (size_t)jn * ND + ko);
    WhN[kt] = *reinterpret_cast<const bf16x8*>(Whh + (size_t)jn * ND + ko);
  }
  const float bir = bih[jr] + bhh[jr];
  const float biz = bih[jz] + bhh[jz];
  const float bin = bih[jn], bhn = bhh[jn];

#pragma unroll
  for (int rt = 0; rt < 4; ++rt) {
    int na = n0 + rt * 16 + lm;
    bf16x8 aA[4], aX[4];
#pragma unroll
    for (int kt = 0; kt < 4; ++kt) {
      int ko = kt * 32 + l4 * 8;
      bf16x8 z8 = {};
      aA[kt] = (na < N) ? *reinterpret_cast<const bf16x8*>(aggb + (size_t)na * ND + ko) : z8;
      aX[kt] = (na < N) ? *reinterpret_cast<const bf16x8*>(xb + (size_t)na * ND + ko) : z8;
    }
    f32x4 aR = {0.f,0.f,0.f,0.f}, aZ = {0.f,0.f,0.f,0.f};
    f32x4 ai = {0.f,0.f,0.f,0.f}, ah = {0.f,0.f,0.f,0.f};
#pragma unroll
    for (int kt = 0; kt < 4; ++kt) {
      aR = mfma_bf16(aA[kt], WiR[kt], aR);
      aR = mfma_bf16(aX[kt], WhR[kt], aR);
      aZ = mfma_bf16(aA[kt], WiZ[kt], aZ);
      aZ = mfma_bf16(aX[kt], WhZ[kt], aZ);
      ai = mfma_bf16(aA[kt], WiN[kt], ai);
      ah = mfma_bf16(aX[kt], WhN[kt], ah);
    }
#pragma unroll
    for (int rr = 0; rr < 4; ++rr) {
      int node = n0 + rt * 16 + l4 * 4 + rr;
      if (node < N) {
        float r = fast_sigmoid(aR[rr] + bir);
        float z = fast_sigmoid(aZ[rr] + biz);
        float n = fast_tanh(ai[rr] + bin + r * (ah[rr] + bhn));
        float xv = x[(size_t)node * ND + jr];
        out[(size_t)node * ND + jr] = (1.f - z) * n + z * xv;
      }
    }
  }
}

extern "C" void kernel_launch(void* const* d_in, const int* in_sizes, int n_in,
                              void* d_out, int out_size, void* d_ws, size_t ws_size,
                              hipStream_t stream) {
  const float* x   = (const float*)d_in[0];
  const int*   ei  = (const int*)d_in[1];
  const float* ea  = (const float*)d_in[2];
  const float* W1  = (const float*)d_in[3];
  const float* b1  = (const float*)d_in[4];
  const float* W2  = (const float*)d_in[5];
  const float* b2  = (const float*)d_in[6];
  const float* Wih = (const float*)d_in[7];
  const float* bih = (const float*)d_in[8];
  const float* Whh = (const float*)d_in[9];
  const float* bhh = (const float*)d_in[10];
  float* out = (float*)d_out;
  const int N = in_sizes[0] / ND;       // 50000
  const int E = in_sizes[1] / 2;        // 800000

  const int nb = (N + 255) / 256;       // scan blocks (196)
  const int nC = nb * 256;              // padded counts (50176)

  char* ws = (char*)d_ws;
  size_t off = 0;
  auto alloc = [&](size_t bytes) -> void* {
    void* p = ws + off;
    off += (bytes + 255) & ~(size_t)255;
    return p;
  };
  __bf16* xb   = (__bf16*)alloc((size_t)N * ND * 2);
  __bf16* aggb = (__bf16*)alloc((size_t)N * ND * 2);
  __bf16* W1b  = (__bf16*)alloc(128 * 160 * 2);
  __bf16* W2b  = (__bf16*)alloc(128 * 128 * 2);
  __bf16* Wihb = (__bf16*)alloc(384 * 128 * 2);
  __bf16* Whhb = (__bf16*)alloc(384 * 128 * 2);
  size_t common_off = off;

  // sort-path extras
  int*    counts  = (int*)alloc((size_t)nC * 4);
  int*    offsets = (int*)alloc((size_t)(nC + 16) * 4);
  int*    cursor  = (int*)alloc((size_t)nC * 4);
  int*    bsum    = (int*)alloc(256 * 4);
  int*    spos    = (int*)alloc((size_t)E * 4);
  __bf16* mbuf    = (__bf16*)alloc((size_t)E * HID * 2);
  size_t need_sort = off;

  bool use_sort = (ws_size >= need_sort);

  cvt_f32_bf16<<<(N * ND / 8 + 255) / 256, 256, 0, stream>>>(x, xb, N * ND / 8);
  cvt_f32_bf16<<<(128 * 160 / 8 + 255) / 256, 256, 0, stream>>>(W1, W1b, 128 * 160 / 8);
  cvt_f32_bf16<<<(128 * 128 / 8 + 255) / 256, 256, 0, stream>>>(W2, W2b, 128 * 128 / 8);
  cvt_f32_bf16<<<(384 * 128 / 8 + 255) / 256, 256, 0, stream>>>(Wih, Wihb, 384 * 128 / 8);
  cvt_f32_bf16<<<(384 * 128 / 8 + 255) / 256, 256, 0, stream>>>(Whh, Whhb, 384 * 128 / 8);

  const int ntiles = E / TILE_E;
  const int* dstp = ei + E;

  if (use_sort) {
    hipMemsetAsync(counts, 0, (size_t)nC * 4, stream);
    k_hist<<<(E + 255) / 256, 256, 0, stream>>>(dstp, counts, E);
    k_blocksum<<<nb, 256, 0, stream>>>(counts, bsum);
    k_scan_bsum<<<1, 256, 0, stream>>>(bsum, nb);
    k_scan_write<<<nb, 256, 0, stream>>>(counts, bsum, offsets, cursor);
    k_spos<<<(E + 255) / 256, 256, 0, stream>>>(dstp, cursor, spos, E);
    edge_mlp<1><<<2500, 512, 0, stream>>>(xb, ei, ea, W1b, b1, W2b, b2,
                                          nullptr, mbuf, spos, E, ntiles);
    k_aggregate<<<(N + 3) / 4, 256, 0, stream>>>(mbuf, offsets, aggb, N);
  } else {
    // fallback: atomic scatter into f32 agg (fits in ~52 MB of ws)
    off = common_off;
    float* aggf = (float*)alloc((size_t)N * ND * 4);
    hipMemsetAsync(aggf, 0, (size_t)N * ND * 4, stream);
    edge_mlp<0><<<2500, 512, 0, stream>>>(xb, ei, ea, W1b, b1, W2b, b2,
                                          aggf, nullptr, nullptr, E, ntiles);
    cvt_f32_bf16<<<(N * ND / 8 + 255) / 256, 256, 0, stream>>>(aggf, aggb, N * ND / 8);
  }

  gru2<<<(N + 63) / 64, 512, 0, stream>>>(aggb, xb, x, Wihb, bih, Whhb, bhh, out, N);
}

// Round 3
// 378.813 us; speedup vs baseline: 1.2242x; 1.0237x over previous
//
#include <hip/hip_runtime.h>
#include <hip/hip_bf16.h>
#include <cstdint>

typedef __bf16 bf16x8 __attribute__((ext_vector_type(8)));
typedef __bf16 bf16x4 __attribute__((ext_vector_type(4)));
typedef float  f32x4  __attribute__((ext_vector_type(4)));

#define ND 128
#define HID 128

__device__ __forceinline__ f32x4 mfma_bf16(bf16x8 a, bf16x8 b, f32x4 c) {
  return __builtin_amdgcn_mfma_f32_16x16x32_bf16(a, b, c, 0, 0, 0);
}
__device__ __forceinline__ float fast_sigmoid(float x) {
  return __fdividef(1.f, 1.f + __expf(-x));
}
__device__ __forceinline__ float fast_silu(float x) {
  return __fdividef(x, 1.f + __expf(-x));
}
__device__ __forceinline__ float fast_tanh(float x) {
  float cx = fminf(fmaxf(x, -15.f), 15.f);
  float e = __expf(2.f * cx);
  return __fdividef(e - 1.f, e + 1.f);
}

// ---- fused f32 -> bf16 conversion over 5 segments ----
__global__ void cvt_all(const float* __restrict__ s0, __bf16* __restrict__ d0, int c1,
                        const float* __restrict__ s1, __bf16* __restrict__ d1, int c2,
                        const float* __restrict__ s2, __bf16* __restrict__ d2, int c3,
                        const float* __restrict__ s3, __bf16* __restrict__ d3, int c4,
                        const float* __restrict__ s4, __bf16* __restrict__ d4, int c5) {
  int i = blockIdx.x * blockDim.x + threadIdx.x;
  const float* s; __bf16* d; int j;
  if (i < c1)      { s = s0; d = d0; j = i; }
  else if (i < c2) { s = s1; d = d1; j = i - c1; }
  else if (i < c3) { s = s2; d = d2; j = i - c2; }
  else if (i < c4) { s = s3; d = d3; j = i - c3; }
  else if (i < c5) { s = s4; d = d4; j = i - c4; }
  else return;
  const float4* sp = reinterpret_cast<const float4*>(s) + (size_t)j * 2;
  float4 a = sp[0], b = sp[1];
  bf16x8 v;
  v[0] = (__bf16)a.x; v[1] = (__bf16)a.y; v[2] = (__bf16)a.z; v[3] = (__bf16)a.w;
  v[4] = (__bf16)b.x; v[5] = (__bf16)b.y; v[6] = (__bf16)b.z; v[7] = (__bf16)b.w;
  reinterpret_cast<bf16x8*>(d)[j] = v;
}

// ================= sort machinery =================
__global__ void k_hist(const int* __restrict__ dst, int* __restrict__ counts, int E) {
  int e = blockIdx.x * 256 + threadIdx.x;
  if (e < E) atomicAdd(&counts[dst[e]], 1);
}

__global__ void k_blocksum(const int* __restrict__ counts, int* __restrict__ bsum) {
  __shared__ int sd[256];
  int t = threadIdx.x;
  sd[t] = counts[blockIdx.x * 256 + t];
  __syncthreads();
  for (int d = 128; d > 0; d >>= 1) { if (t < d) sd[t] += sd[t + d]; __syncthreads(); }
  if (!t) bsum[blockIdx.x] = sd[0];
}

__global__ void k_scan_bsum(int* __restrict__ bsum, int nb) {
  __shared__ int sd[256];
  int t = threadIdx.x;
  int v = (t < nb) ? bsum[t] : 0;
  sd[t] = v;
  __syncthreads();
  for (int d = 1; d < 256; d <<= 1) {
    int u = (t >= d) ? sd[t - d] : 0;
    __syncthreads();
    sd[t] += u;
    __syncthreads();
  }
  if (t < nb) bsum[t] = sd[t] - v;
}

__global__ void k_scan_write(const int* __restrict__ counts, const int* __restrict__ bsum,
                             int* __restrict__ offsets, int* __restrict__ cursor) {
  __shared__ int sd[256];
  int t = threadIdx.x, b = blockIdx.x;
  int i = b * 256 + t;
  int c = counts[i];
  sd[t] = c;
  __syncthreads();
  for (int d = 1; d < 256; d <<= 1) {
    int u = (t >= d) ? sd[t - d] : 0;
    __syncthreads();
    sd[t] += u;
    __syncthreads();
  }
  int excl = bsum[b] + sd[t] - c;
  offsets[i] = excl;
  cursor[i]  = excl;
  if (b == (int)gridDim.x - 1 && t == 255) offsets[i + 1] = excl + c;
}

__global__ void k_spos(const int* __restrict__ dst, int* __restrict__ cursor,
                       int* __restrict__ spos, int E) {
  int e = blockIdx.x * 256 + threadIdx.x;
  if (e < E) spos[e] = atomicAdd(&cursor[dst[e]], 1);
}

// ================= edge MLP (weights-as-A, transposed output) =================
#define TILE_E 64
// A tile: [64 edges][192 bf16] = 384B rows (bank-aligned), 16B-chunk XOR swizzle
// H1 tile: [64 edges][128 bf16] = 256B rows, same swizzle

template <int SORT>
__global__ __launch_bounds__(256) void edge_mlp(
    const __bf16* __restrict__ xb,
    const int*    __restrict__ ei,     // [2*E]: src then dst
    const float*  __restrict__ ea,     // [E,32]
    const __bf16* __restrict__ W1b,    // [128,160]
    const float*  __restrict__ b1,
    const __bf16* __restrict__ W2b,    // [128,128]
    const float*  __restrict__ b2,
    float*  __restrict__ agg,          // SORT==0
    __bf16* __restrict__ mbuf,         // SORT==1
    const int* __restrict__ spos,
    int E, int ntiles)
{
  __shared__ __bf16 Als[TILE_E * 192];
  __shared__ __bf16 H1[TILE_E * 128];
  __shared__ int sposls[TILE_E];
  char* AlsB = (char*)Als;
  char* H1B  = (char*)H1;

  const int tid = threadIdx.x;
  const int w  = tid >> 6;      // wave 0..3 -> j-strip of 32
  const int l  = tid & 63;
  const int l4 = l >> 4;
  const int lm = l & 15;
  const int jb = w * 32;

  // Weight fragments (A-operand): row = jb + jt*16 + lm, k = kt*32 + l4*8
  bf16x8 bw1[2][5], bw2[2][4];
#pragma unroll
  for (int jt = 0; jt < 2; ++jt) {
    const int jr = jb + jt * 16 + lm;
#pragma unroll
    for (int kt = 0; kt < 5; ++kt)
      bw1[jt][kt] = *reinterpret_cast<const bf16x8*>(W1b + (size_t)jr * 160 + kt * 32 + l4 * 8);
#pragma unroll
    for (int kt = 0; kt < 4; ++kt)
      bw2[jt][kt] = *reinterpret_cast<const bf16x8*>(W2b + (size_t)jr * 128 + kt * 32 + l4 * 8);
  }
  // biases for C rows j = jb + jt*16 + l4*4 + rr
  float4 b1v[2], b2v[2];
#pragma unroll
  for (int jt = 0; jt < 2; ++jt) {
    b1v[jt] = *reinterpret_cast<const float4*>(b1 + jb + jt * 16 + l4 * 4);
    b2v[jt] = *reinterpret_cast<const float4*>(b2 + jb + jt * 16 + l4 * 4);
  }
  const int* srcp = ei;
  const int* dstp = ei + E;

  for (int tile = blockIdx.x; tile < ntiles; tile += gridDim.x) {
    const int e0 = tile * TILE_E;

    // ---- stage A tile (swizzled): x part 1024 chunks, ea part 512 half-chunks
#pragma unroll
    for (int it = 0; it < 4; ++it) {
      int idx = it * 256 + tid;
      int e = idx >> 4, q = idx & 15;
      int s = srcp[e0 + e];
      bf16x8 v = *reinterpret_cast<const bf16x8*>(xb + (size_t)s * ND + q * 8);
      *reinterpret_cast<bf16x8*>(AlsB + e * 384 + ((q ^ (e & 7)) << 4)) = v;
    }
#pragma unroll
    for (int it = 0; it < 2; ++it) {
      int idx = it * 256 + tid;
      int e = idx >> 3, q = idx & 7;
      float4 v = reinterpret_cast<const float4*>(ea)[(size_t)(e0 + e) * 8 + q];
      bf16x4 h;
      h[0] = (__bf16)v.x; h[1] = (__bf16)v.y; h[2] = (__bf16)v.z; h[3] = (__bf16)v.w;
      int chunk = 16 + (q >> 1);
      *reinterpret_cast<bf16x4*>(AlsB + e * 384 + ((chunk ^ (e & 7)) << 4) + ((q & 1) << 3)) = h;
    }
    if (SORT && tid < TILE_E) sposls[tid] = spos[e0 + tid];
    __syncthreads();

    // ---- layer 1: H1^T[j][e] = silu(W1 . A^T), write H1[e][j] packed b64
#pragma unroll
    for (int et = 0; et < 4; ++et) {
      const int e = et * 16 + lm;
      const int sw = (lm & 7);
      f32x4 acc0 = {0.f, 0.f, 0.f, 0.f}, acc1 = {0.f, 0.f, 0.f, 0.f};
#pragma unroll
      for (int kt = 0; kt < 5; ++kt) {
        bf16x8 bfrag = *reinterpret_cast<const bf16x8*>(AlsB + e * 384 + (((kt * 4 + l4) ^ sw) << 4));
        acc0 = mfma_bf16(bw1[0][kt], bfrag, acc0);
        acc1 = mfma_bf16(bw1[1][kt], bfrag, acc1);
      }
      // lane holds C rows j = jb + jt*16 + l4*4 + rr, col e (same e as read row)
      bf16x4 h0, h1;
#pragma unroll
      for (int rr = 0; rr < 4; ++rr) {
        h0[rr] = (__bf16)fast_silu(acc0[rr] + (&b1v[0].x)[rr]);
        h1[rr] = (__bf16)fast_silu(acc1[rr] + (&b1v[1].x)[rr]);
      }
      int c0 = (jb >> 3) + (l4 >> 1);       // chunk of j0 = jb + l4*4
      int inner = (l4 & 1) << 3;
      *reinterpret_cast<bf16x4*>(H1B + e * 256 + ((c0 ^ sw) << 4) + inner) = h0;
      *reinterpret_cast<bf16x4*>(H1B + e * 256 + (((c0 + 2) ^ sw) << 4) + inner) = h1;
    }
    __syncthreads();

    // ---- layer 2: M^T[j][e] = silu(W2 . H1^T); direct 8B stores to mbuf
#pragma unroll
    for (int et = 0; et < 4; ++et) {
      const int e = et * 16 + lm;
      const int sw = (lm & 7);
      f32x4 acc0 = {0.f, 0.f, 0.f, 0.f}, acc1 = {0.f, 0.f, 0.f, 0.f};
#pragma unroll
      for (int kt = 0; kt < 4; ++kt) {
        bf16x8 bfrag = *reinterpret_cast<const bf16x8*>(H1B + e * 256 + (((kt * 4 + l4) ^ sw) << 4));
        acc0 = mfma_bf16(bw2[0][kt], bfrag, acc0);
        acc1 = mfma_bf16(bw2[1][kt], bfrag, acc1);
      }
      if (SORT) {
        bf16x4 m0, m1;
#pragma unroll
        for (int rr = 0; rr < 4; ++rr) {
          m0[rr] = (__bf16)fast_silu(acc0[rr] + (&b2v[0].x)[rr]);
          m1[rr] = (__bf16)fast_silu(acc1[rr] + (&b2v[1].x)[rr]);
        }
        int sp = sposls[e];
        __bf16* rowp = mbuf + (size_t)sp * HID + jb + l4 * 4;
        *reinterpret_cast<bf16x4*>(rowp)      = m0;
        *reinterpret_cast<bf16x4*>(rowp + 16) = m1;
      } else {
        int d = dstp[e0 + e];
#pragma unroll
        for (int rr = 0; rr < 4; ++rr) {
          atomicAdd(agg + (size_t)d * HID + jb + l4 * 4 + rr,
                    fast_silu(acc0[rr] + (&b2v[0].x)[rr]));
          atomicAdd(agg + (size_t)d * HID + jb + 16 + l4 * 4 + rr,
                    fast_silu(acc1[rr] + (&b2v[1].x)[rr]));
        }
      }
    }
    __syncthreads();
  }
}

// ================= aggregator: one wave per node =================
__global__ __launch_bounds__(256) void k_aggregate(
    const __bf16* __restrict__ mbuf, const int* __restrict__ offsets,
    __bf16* __restrict__ aggb, int N)
{
  int node = blockIdx.x * 4 + (threadIdx.x >> 6);
  int l = threadIdx.x & 63;
  if (node >= N) return;
  int lo = offsets[node], hi = offsets[node + 1];
  int cnt = hi - lo;
  float s0 = 0.f, s1 = 0.f;
  const uint32_t* p = reinterpret_cast<const uint32_t*>(mbuf) + (size_t)lo * 64 + l;
  int r = 0;
  for (; r + 4 <= cnt; r += 4) {
    uint32_t u0 = p[0], u1 = p[64], u2 = p[128], u3 = p[192];
    p += 256;
    s0 += __uint_as_float(u0 << 16) + __uint_as_float(u1 << 16)
        + __uint_as_float(u2 << 16) + __uint_as_float(u3 << 16);
    s1 += __uint_as_float(u0 & 0xffff0000u) + __uint_as_float(u1 & 0xffff0000u)
        + __uint_as_float(u2 & 0xffff0000u) + __uint_as_float(u3 & 0xffff0000u);
  }
  for (; r < cnt; ++r) {
    uint32_t u = p[0];
    p += 64;
    s0 += __uint_as_float(u << 16);
    s1 += __uint_as_float(u & 0xffff0000u);
  }
  uint32_t o = (uint32_t)__builtin_bit_cast(unsigned short, (__bf16)s0) |
               ((uint32_t)__builtin_bit_cast(unsigned short, (__bf16)s1) << 16);
  reinterpret_cast<uint32_t*>(aggb)[(size_t)node * 64 + l] = o;
}

// ================= GRU (weights-as-A, transposed, no LDS) =================
__global__ __launch_bounds__(512) void gru2(
    const __bf16* __restrict__ aggb,
    const __bf16* __restrict__ xb,
    const float*  __restrict__ x,
    const __bf16* __restrict__ Wih, const float* __restrict__ bih,  // [384,128]
    const __bf16* __restrict__ Whh, const float* __restrict__ bhh,
    float* __restrict__ out, int N)
{
  const int tid = threadIdx.x;
  const int w = tid >> 6, l = tid & 63;
  const int l4 = l >> 4, lm = l & 15;
  const int n0 = blockIdx.x * 64;
  const int jb = w * 16;
  const int jr = jb + lm, jz = jr + 128, jn = jr + 256;

  bf16x8 WiR[4], WhR[4], WiZ[4], WhZ[4], WiN[4], WhN[4];
#pragma unroll
  for (int kt = 0; kt < 4; ++kt) {
    int ko = kt * 32 + l4 * 8;
    WiR[kt] = *reinterpret_cast<const bf16x8*>(Wih + (size_t)jr * ND + ko);
    WhR[kt] = *reinterpret_cast<const bf16x8*>(Whh + (size_t)jr * ND + ko);
    WiZ[kt] = *reinterpret_cast<const bf16x8*>(Wih + (size_t)jz * ND + ko);
    WhZ[kt] = *reinterpret_cast<const bf16x8*>(Whh + (size_t)jz * ND + ko);
    WiN[kt] = *reinterpret_cast<const bf16x8*>(Wih + (size_t)jn * ND + ko);
    WhN[kt] = *reinterpret_cast<const bf16x8*>(Whh + (size_t)jn * ND + ko);
  }
  // biases for C rows j = jb + l4*4 + rr
  float4 birv, bizv, binv, bhnv;
  {
    int j0 = jb + l4 * 4;
    float4 a = *reinterpret_cast<const float4*>(bih + j0);
    float4 b = *reinterpret_cast<const float4*>(bhh + j0);
    birv = make_float4(a.x + b.x, a.y + b.y, a.z + b.z, a.w + b.w);
    a = *reinterpret_cast<const float4*>(bih + 128 + j0);
    b = *reinterpret_cast<const float4*>(bhh + 128 + j0);
    bizv = make_float4(a.x + b.x, a.y + b.y, a.z + b.z, a.w + b.w);
    binv = *reinterpret_cast<const float4*>(bih + 256 + j0);
    bhnv = *reinterpret_cast<const float4*>(bhh + 256 + j0);
  }

#pragma unroll
  for (int rt = 0; rt < 4; ++rt) {
    const int node = n0 + rt * 16 + lm;   // B-frag col = C col
    const bool ok = node < N;
    bf16x8 aA[4], aX[4];
#pragma unroll
    for (int kt = 0; kt < 4; ++kt) {
      int ko = kt * 32 + l4 * 8;
      bf16x8 z8 = {};
      aA[kt] = ok ? *reinterpret_cast<const bf16x8*>(aggb + (size_t)node * ND + ko) : z8;
      aX[kt] = ok ? *reinterpret_cast<const bf16x8*>(xb + (size_t)node * ND + ko) : z8;
    }
    f32x4 aR = {0.f,0.f,0.f,0.f}, aZ = {0.f,0.f,0.f,0.f};
    f32x4 ai = {0.f,0.f,0.f,0.f}, ah = {0.f,0.f,0.f,0.f};
#pragma unroll
    for (int kt = 0; kt < 4; ++kt) {
      aR = mfma_bf16(WiR[kt], aA[kt], aR);
      aR = mfma_bf16(WhR[kt], aX[kt], aR);
      aZ = mfma_bf16(WiZ[kt], aA[kt], aZ);
      aZ = mfma_bf16(WhZ[kt], aX[kt], aZ);
      ai = mfma_bf16(WiN[kt], aA[kt], ai);
      ah = mfma_bf16(WhN[kt], aX[kt], ah);
    }
    if (ok) {
      float4 xv = *reinterpret_cast<const float4*>(x + (size_t)node * ND + jb + l4 * 4);
      float4 ov;
#pragma unroll
      for (int rr = 0; rr < 4; ++rr) {
        float r = fast_sigmoid(aR[rr] + (&birv.x)[rr]);
        float z = fast_sigmoid(aZ[rr] + (&bizv.x)[rr]);
        float n = fast_tanh(ai[rr] + (&binv.x)[rr] + r * (ah[rr] + (&bhnv.x)[rr]));
        (&ov.x)[rr] = (1.f - z) * n + z * (&xv.x)[rr];
      }
      *reinterpret_cast<float4*>(out + (size_t)node * ND + jb + l4 * 4) = ov;
    }
  }
}

extern "C" void kernel_launch(void* const* d_in, const int* in_sizes, int n_in,
                              void* d_out, int out_size, void* d_ws, size_t ws_size,
                              hipStream_t stream) {
  const float* x   = (const float*)d_in[0];
  const int*   ei  = (const int*)d_in[1];
  const float* ea  = (const float*)d_in[2];
  const float* W1  = (const float*)d_in[3];
  const float* b1  = (const float*)d_in[4];
  const float* W2  = (const float*)d_in[5];
  const float* b2  = (const float*)d_in[6];
  const float* Wih = (const float*)d_in[7];
  const float* bih = (const float*)d_in[8];
  const float* Whh = (const float*)d_in[9];
  const float* bhh = (const float*)d_in[10];
  float* out = (float*)d_out;
  const int N = in_sizes[0] / ND;       // 50000
  const int E = in_sizes[1] / 2;        // 800000

  const int nb = (N + 255) / 256;
  const int nC = nb * 256;

  char* ws = (char*)d_ws;
  size_t off = 0;
  auto alloc = [&](size_t bytes) -> void* {
    void* p = ws + off;
    off += (bytes + 255) & ~(size_t)255;
    return p;
  };
  __bf16* xb   = (__bf16*)alloc((size_t)N * ND * 2);
  __bf16* aggb = (__bf16*)alloc((size_t)N * ND * 2);
  __bf16* W1b  = (__bf16*)alloc(128 * 160 * 2);
  __bf16* W2b  = (__bf16*)alloc(128 * 128 * 2);
  __bf16* Wihb = (__bf16*)alloc(384 * 128 * 2);
  __bf16* Whhb = (__bf16*)alloc(384 * 128 * 2);
  size_t common_off = off;

  int*    counts  = (int*)alloc((size_t)nC * 4);
  int*    offsets = (int*)alloc((size_t)(nC + 16) * 4);
  int*    cursor  = (int*)alloc((size_t)nC * 4);
  int*    bsum    = (int*)alloc(256 * 4);
  int*    spos    = (int*)alloc((size_t)E * 4);
  __bf16* mbuf    = (__bf16*)alloc((size_t)E * HID * 2);
  size_t need_sort = off;

  bool use_sort = (ws_size >= need_sort);

  // fused conversions
  const int n8_x = N * ND / 8, n8_1 = 128 * 160 / 8, n8_2 = 128 * 128 / 8, n8_g = 384 * 128 / 8;
  int c1 = n8_x, c2 = c1 + n8_1, c3 = c2 + n8_2, c4 = c3 + n8_g, c5 = c4 + n8_g;
  cvt_all<<<(c5 + 255) / 256, 256, 0, stream>>>(x, xb, c1, W1, W1b, c2, W2, W2b, c3,
                                                Wih, Wihb, c4, Whh, Whhb, c5);

  const int ntiles = E / TILE_E;
  const int* dstp = ei + E;

  if (use_sort) {
    hipMemsetAsync(counts, 0, (size_t)nC * 4, stream);
    k_hist<<<(E + 255) / 256, 256, 0, stream>>>(dstp, counts, E);
    k_blocksum<<<nb, 256, 0, stream>>>(counts, bsum);
    k_scan_bsum<<<1, 256, 0, stream>>>(bsum, nb);
    k_scan_write<<<nb, 256, 0, stream>>>(counts, bsum, offsets, cursor);
    k_spos<<<(E + 255) / 256, 256, 0, stream>>>(dstp, cursor, spos, E);
    edge_mlp<1><<<2500, 256, 0, stream>>>(xb, ei, ea, W1b, b1, W2b, b2,
                                          nullptr, mbuf, spos, E, ntiles);
    k_aggregate<<<(N + 3) / 4, 256, 0, stream>>>(mbuf, offsets, aggb, N);
  } else {
    off = common_off;
    float* aggf = (float*)alloc((size_t)N * ND * 4);
    hipMemsetAsync(aggf, 0, (size_t)N * ND * 4, stream);
    edge_mlp<0><<<2500, 256, 0, stream>>>(xb, ei, ea, W1b, b1, W2b, b2,
                                          aggf, nullptr, nullptr, E, ntiles);
    cvt_all<<<(n8_x + 255) / 256, 256, 0, stream>>>(aggf, aggb, n8_x,
                                                    nullptr, nullptr, n8_x,
                                                    nullptr, nullptr, n8_x,
                                                    nullptr, nullptr, n8_x,
                                                    nullptr, nullptr, n8_x);
  }

  gru2<<<(N + 63) / 64, 512, 0, stream>>>(aggb, xb, x, Wihb, bih, Whhb, bhh, out, N);
}